// Round 10
// baseline (239.530 us; speedup 1.0000x reference)
//
#include <hip/hip_runtime.h>
#include <hip/hip_bf16.h>

#define BB 4
#define NN 128
#define NH 8

typedef __attribute__((ext_vector_type(8))) short short8;
typedef __attribute__((ext_vector_type(4))) float f32x4;

__device__ __forceinline__ float lrelu(float x){ return fmaxf(x, 0.1f*x); }
__device__ __forceinline__ unsigned short f2b(float x){
  __hip_bfloat16 h = __float2bfloat16(x);
  return *reinterpret_cast<unsigned short*>(&h);
}
__device__ __forceinline__ short8 ldf(const unsigned short* p){ return *(const short8*)p; }

// wbf ushort offsets: WssT 0 [512x128] | WeoT 65536 [128x256] | We1T 98304 [128x128]
// We2T 114688 [128x128] | WqkvT 131072 [768x256] | WnoT 327680 [256x256]
// Wn1T 393216 [1024x256] | Wn2T 655360 [256x1024]

// ---- setup: LDS-tiled bf16 transposes (tiles 0..895) + cond GEMM (896..911) ----
__global__ __launch_bounds__(256) void k_setup(
    const float* Wss, const float* Weo, const float* We1, const float* We2,
    const float* Wqkv, const float* Wno, const float* Wn1, const float* Wn2,
    const float* conds, const float* Wc, const float* bc,
    unsigned short* wbf, float* cond){
  __shared__ float tile[32][33];
  __shared__ float c[256];
  int bid = blockIdx.x, t = threadIdx.x;
  if (bid < 896){
    const float* src; int K, N; size_t doff; int tid;
    if      (bid < 64)  { src=Wss;  K=128;  N=512;  doff=0;      tid=bid; }
    else if (bid < 96)  { src=Weo;  K=256;  N=128;  doff=65536;  tid=bid-64; }
    else if (bid < 112) { src=We1;  K=128;  N=128;  doff=98304;  tid=bid-96; }
    else if (bid < 128) { src=We2;  K=128;  N=128;  doff=114688; tid=bid-112; }
    else if (bid < 320) { src=Wqkv; K=256;  N=768;  doff=131072; tid=bid-128; }
    else if (bid < 384) { src=Wno;  K=256;  N=256;  doff=327680; tid=bid-320; }
    else if (bid < 640) { src=Wn1;  K=256;  N=1024; doff=393216; tid=bid-384; }
    else                { src=Wn2;  K=1024; N=256;  doff=655360; tid=bid-640; }
    int ntk = K >> 5;
    int k0 = (tid % ntk) * 32, n0 = (tid / ntk) * 32;
    int r = t >> 3, c4 = (t & 7) * 4;
    float4 v = *(const float4*)(src + (size_t)(k0+r)*N + n0 + c4);
    tile[r][c4+0]=v.x; tile[r][c4+1]=v.y; tile[r][c4+2]=v.z; tile[r][c4+3]=v.w;
    __syncthreads();
    ushort4 o;
    o.x = f2b(tile[c4+0][r]); o.y = f2b(tile[c4+1][r]);
    o.z = f2b(tile[c4+2][r]); o.w = f2b(tile[c4+3][r]);
    *(ushort4*)(wbf + doff + (size_t)(n0+r)*K + k0 + c4) = o;
  } else {
    int i = bid - 896;
    int b = i >> 2, j = (i&3)*256 + t;
    c[t] = conds[(size_t)b*256 + t];
    __syncthreads();
    float acc = bc[j];
    for (int kk = 0; kk < 256; kk++) acc += c[kk]*Wc[(size_t)kk*1024 + j];
    cond[b*1024 + j] = acc;
  }
}

// ---- film1 + qkv (MFMA). 16 rows x 192-col slice per block, grid 128 ----
#define NSTR 260
__global__ __launch_bounds__(256) void k_nodeA(const float* __restrict__ nodes,
    const float* __restrict__ cond, const unsigned short* __restrict__ WqkvT,
    const float* __restrict__ bqkv, float* __restrict__ qbuf,
    float* __restrict__ kT, unsigned short* __restrict__ vT){
  __shared__ float nbuf[16*NSTR];
  __shared__ __align__(16) unsigned short abuf[16*272];
  __shared__ float psum[256], psq[256], mrow[16], irow[16];
  int t = threadIdx.x;
  int rg = blockIdx.x >> 2, slice = blockIdx.x & 3;
  int b = rg >> 3, n0 = (rg & 7)*16;
  int l = t & 63, w = t >> 6, l15 = l & 15, q = l >> 4;

  const float4* src = (const float4*)(nodes + ((size_t)(b*128+n0))*256);
  #pragma unroll
  for (int i = 0; i < 4; i++){
    int f = t + i*256; int r = f >> 6, c4 = f & 63;
    *(float4*)(nbuf + r*NSTR + c4*4) = src[f];
  }
  __syncthreads();
  {
    int r = t >> 4, p = t & 15;
    float s = 0.f, s2 = 0.f;
    #pragma unroll
    for (int i = 0; i < 16; i++){ float v = nbuf[r*NSTR + p + 16*i]; s += v; s2 += v*v; }
    psum[t] = s; psq[t] = s2;
  }
  __syncthreads();
  if (t < 16){
    float s = 0.f, s2 = 0.f;
    #pragma unroll
    for (int i = 0; i < 16; i++){ s += psum[t*16+i]; s2 += psq[t*16+i]; }
    float m = s*(1.f/256);
    mrow[t] = m; irow[t] = rsqrtf(s2*(1.f/256) - m*m + 1e-5f);
  }
  __syncthreads();
  #pragma unroll
  for (int i = 0; i < 16; i++){
    int f = t + i*256; int r = f >> 8, cc = f & 255;
    float x = (nbuf[r*NSTR+cc]-mrow[r])*irow[r]*(1.f+cond[b*1024+cc]) + cond[b*1024+256+cc];
    abuf[r*272+cc] = f2b(lrelu(x));
  }
  __syncthreads();
  short8 af[8];
  #pragma unroll
  for (int k = 0; k < 8; k++) af[k] = ldf(abuf + l15*272 + k*32 + q*8);
  #pragma unroll
  for (int tt = 0; tt < 3; tt++){
    int cc = slice*192 + w*48 + tt*16 + l15;
    const unsigned short* bp = WqkvT + (size_t)cc*256 + q*8;
    f32x4 acc = {0.f,0.f,0.f,0.f};
    #pragma unroll
    for (int k = 0; k < 8; k++) acc = __builtin_amdgcn_mfma_f32_16x16x32_bf16(af[k], ldf(bp + k*32), acc,0,0,0);
    float bb = bqkv[cc];
    if (cc < 256){
      #pragma unroll
      for (int r = 0; r < 4; r++) qbuf[(size_t)(b*128+n0+q*4+r)*256 + cc] = acc[r] + bb;
    } else if (cc < 512){
      float4 kv; kv.x = acc[0]+bb; kv.y = acc[1]+bb; kv.z = acc[2]+bb; kv.w = acc[3]+bb;
      *(float4*)(kT + ((size_t)(b*256 + cc-256))*128 + n0 + q*4) = kv;
    } else {
      ushort4 vv; vv.x = f2b(acc[0]+bb); vv.y = f2b(acc[1]+bb); vv.z = f2b(acc[2]+bb); vv.w = f2b(acc[3]+bb);
      *(ushort4*)(vT + ((size_t)(b*256 + cc-512))*128 + n0 + q*4) = vv;
    }
  }
}

// ---- fused edge path, 256 threads, 64 rows/block, grid 1024; 52.2 KB LDS (3 blk/CU) ----
#define ASTR 136
#define LSTR 264
__global__ __launch_bounds__(256) void k_edge(
    const float* __restrict__ edges, const float* __restrict__ qbuf, const float* __restrict__ kT,
    const unsigned short* __restrict__ WssT, const float* __restrict__ bss,
    const unsigned short* __restrict__ WeoT, const float* __restrict__ beo,
    const unsigned short* __restrict__ We1T, const float* __restrict__ be1,
    const unsigned short* __restrict__ We2T, const float* __restrict__ be2,
    float* __restrict__ logits, float* __restrict__ out_edges){
  __shared__ __align__(16) unsigned char SM[52224];
  unsigned short* abuf = (unsigned short*)SM;             // 64*136*2 = 17408 B
  unsigned short* lbuf = (unsigned short*)(SM + 17408);   // 64*264*2 = 33792 B
  float* qvs = (float*)(SM + 51200);                      // 1024 B
  // aliases into lbuf (live only between P2-read barrier and P3 hbuf writes):
  float* redS = (float*)(SM + 17408);          // 1024
  float* redQ = (float*)(SM + 18432);          // 1024
  float* mrow = (float*)(SM + 19456);          // 256
  float* irow = (float*)(SM + 19712);          // 256

  int t = threadIdx.x;
  int p0 = blockIdx.x * 64;
  int b  = p0 >> 14, qi = (p0 >> 7) & 127, ki0 = p0 & 127;   // ki0 in {0,64}
  int w = t >> 6, l15 = t & 15, q = (t & 63) >> 4;

  // P0: stage 64x128 edges + per-row LN (32-lane shuffle) -> abuf
  {
    qvs[t] = qbuf[(size_t)(b*128 + qi)*256 + t];
    const float4* src = (const float4*)(edges + (size_t)p0*128);
    #pragma unroll
    for (int i=0;i<8;i++){
      int idx = t + i*256;
      float4 ev = src[idx];
      int r = idx >> 5, c4 = idx & 31;
      float s  = ev.x + ev.y + ev.z + ev.w;
      float s2 = ev.x*ev.x + ev.y*ev.y + ev.z*ev.z + ev.w*ev.w;
      #pragma unroll
      for (int mm=1; mm<32; mm<<=1){ s += __shfl_xor(s,mm); s2 += __shfl_xor(s2,mm); }
      float m = s*(1.f/128);
      float inv = rsqrtf(s2*(1.f/128) - m*m + 1e-5f);
      ushort4 pk;
      pk.x = f2b(lrelu((ev.x - m)*inv)); pk.y = f2b(lrelu((ev.y - m)*inv));
      pk.z = f2b(lrelu((ev.z - m)*inv)); pk.w = f2b(lrelu((ev.w - m)*inv));
      *(ushort4*)(abuf + r*ASTR + c4*4) = pk;
    }
  }
  __syncthreads();

  // P1: ss GEMM; wave w owns heads {2w,2w+1}; 4 row-strips share every B-frag
  const float isd = 0.17677669529663687f;
  {
    short8 af[4][4];
    #pragma unroll
    for (int s=0;s<4;s++)
      #pragma unroll
      for (int k=0;k<4;k++) af[s][k] = ldf(abuf + (s*16+l15)*ASTR + k*32 + q*8);
    #pragma unroll
    for (int h2=0; h2<2; h2++){
      int h = w*2 + h2;
      float ps[4][4] = {{0,0,0,0},{0,0,0,0},{0,0,0,0},{0,0,0,0}};
      #pragma unroll
      for (int tt=0; tt<2; tt++){
        int cc = h*32 + tt*16 + l15;
        const unsigned short* bsp = WssT + (size_t)cc*128 + q*8;
        const unsigned short* bcp = WssT + (size_t)(cc+256)*128 + q*8;
        f32x4 aS[4], aC[4];
        #pragma unroll
        for (int s=0;s<4;s++){ aS[s]={0.f,0.f,0.f,0.f}; aC[s]={0.f,0.f,0.f,0.f}; }
        #pragma unroll
        for (int k=0;k<4;k++){
          short8 b0 = ldf(bsp + k*32);
          short8 b1 = ldf(bcp + k*32);
          #pragma unroll
          for (int s=0;s<4;s++){
            aS[s] = __builtin_amdgcn_mfma_f32_16x16x32_bf16(af[s][k], b0, aS[s],0,0,0);
            aC[s] = __builtin_amdgcn_mfma_f32_16x16x32_bf16(af[s][k], b1, aC[s],0,0,0);
          }
        }
        float bS = bss[cc], bC = bss[256+cc], qv = qvs[cc];
        #pragma unroll
        for (int s=0;s<4;s++){
          float4 kv4 = *(const float4*)(kT + ((size_t)(b*256+cc))*128 + ki0 + s*16 + q*4);
          float kvv[4] = {kv4.x, kv4.y, kv4.z, kv4.w};
          #pragma unroll
          for (int r=0;r<4;r++){
            int row = s*16 + q*4 + r;
            float ne = qv*kvv[r]*(1.f + aC[s][r] + bC) + aS[s][r] + bS;
            lbuf[row*LSTR + cc] = f2b(lrelu(ne));
            ps[s][r] += ne;
          }
        }
      }
      #pragma unroll
      for (int s=0;s<4;s++)
        #pragma unroll
        for (int r=0;r<4;r++){
          float v = ps[s][r];
          v += __shfl_xor(v,1); v += __shfl_xor(v,2);
          v += __shfl_xor(v,4); v += __shfl_xor(v,8);
          if (l15 == 0){
            int ki = ki0 + s*16 + q*4 + r;
            logits[((size_t)(b*8+h)*128 + qi)*128 + ki] = v * isd;
          }
        }
    }
  }
  __syncthreads();

  // P2: Weo GEMM (K=256) + residual; wave w cols [w*32,+32), 4 strips
  float res[2][4][4];
  {
    f32x4 acc[2][4];
    #pragma unroll
    for (int tt=0;tt<2;tt++)
      #pragma unroll
      for (int s=0;s<4;s++) acc[tt][s] = {0.f,0.f,0.f,0.f};
    #pragma unroll
    for (int k=0;k<8;k++){
      short8 lf[4];
      #pragma unroll
      for (int s=0;s<4;s++) lf[s] = ldf(lbuf + (s*16+l15)*LSTR + k*32 + q*8);
      #pragma unroll
      for (int tt=0;tt<2;tt++){
        int ec = w*32 + tt*16 + l15;
        short8 bf = ldf(WeoT + (size_t)ec*256 + k*32 + q*8);
        #pragma unroll
        for (int s=0;s<4;s++)
          acc[tt][s] = __builtin_amdgcn_mfma_f32_16x16x32_bf16(lf[s], bf, acc[tt][s],0,0,0);
      }
    }
    #pragma unroll
    for (int tt=0;tt<2;tt++){
      int ec = w*32 + tt*16 + l15;
      float bb = beo[ec];
      #pragma unroll
      for (int s=0;s<4;s++)
        #pragma unroll
        for (int r=0;r<4;r++){
          int row = s*16 + q*4 + r;
          res[tt][s][r] = edges[(size_t)(p0+row)*128 + ec] + acc[tt][s][r] + bb;
        }
    }
  }
  __syncthreads();   // all lbuf reads done before aliased reduction writes
  #pragma unroll
  for (int s=0;s<4;s++)
    #pragma unroll
    for (int r=0;r<4;r++){
      float ps = res[0][s][r] + res[1][s][r];
      float p2 = res[0][s][r]*res[0][s][r] + res[1][s][r]*res[1][s][r];
      ps += __shfl_xor(ps,1); ps += __shfl_xor(ps,2); ps += __shfl_xor(ps,4); ps += __shfl_xor(ps,8);
      p2 += __shfl_xor(p2,1); p2 += __shfl_xor(p2,2); p2 += __shfl_xor(p2,4); p2 += __shfl_xor(p2,8);
      if (l15 == 0){ redS[(s*16+q*4+r)*4 + w] = ps; redQ[(s*16+q*4+r)*4 + w] = p2; }
    }
  __syncthreads();
  if (t < 64){
    float s = redS[t*4]+redS[t*4+1]+redS[t*4+2]+redS[t*4+3];
    float s2 = redQ[t*4]+redQ[t*4+1]+redQ[t*4+2]+redQ[t*4+3];
    float m = s*(1.f/128);
    mrow[t] = m; irow[t] = rsqrtf(s2*(1.f/128) - m*m + 1e-5f);
  }
  __syncthreads();
  #pragma unroll
  for (int tt=0;tt<2;tt++){
    int ec = w*32 + tt*16 + l15;
    #pragma unroll
    for (int s=0;s<4;s++)
      #pragma unroll
      for (int r=0;r<4;r++){
        int row = s*16 + q*4 + r;
        abuf[row*ASTR + ec] = f2b(lrelu((res[tt][s][r] - mrow[row])*irow[row]));
      }
  }
  __syncthreads();

  // P3: We1 GEMM (K=128) -> hbuf (reuse lbuf base at ASTR stride)
  unsigned short* hbuf = lbuf;
  {
    f32x4 acc[2][4];
    #pragma unroll
    for (int tt=0;tt<2;tt++)
      #pragma unroll
      for (int s=0;s<4;s++) acc[tt][s] = {0.f,0.f,0.f,0.f};
    #pragma unroll
    for (int k=0;k<4;k++){
      short8 af2[4];
      #pragma unroll
      for (int s=0;s<4;s++) af2[s] = ldf(abuf + (s*16+l15)*ASTR + k*32 + q*8);
      #pragma unroll
      for (int tt=0;tt<2;tt++){
        int ec = w*32 + tt*16 + l15;
        short8 bf = ldf(We1T + (size_t)ec*128 + k*32 + q*8);
        #pragma unroll
        for (int s=0;s<4;s++)
          acc[tt][s] = __builtin_amdgcn_mfma_f32_16x16x32_bf16(af2[s], bf, acc[tt][s],0,0,0);
      }
    }
    #pragma unroll
    for (int tt=0;tt<2;tt++){
      int ec = w*32 + tt*16 + l15;
      float bb = be1[ec];
      #pragma unroll
      for (int s=0;s<4;s++)
        #pragma unroll
        for (int r=0;r<4;r++)
          hbuf[(s*16+q*4+r)*ASTR + ec] = f2b(lrelu(acc[tt][s][r] + bb));
    }
  }
  __syncthreads();
  // P4: We2 GEMM (K=128) + residual -> out
  {
    f32x4 acc[2][4];
    #pragma unroll
    for (int tt=0;tt<2;tt++)
      #pragma unroll
      for (int s=0;s<4;s++) acc[tt][s] = {0.f,0.f,0.f,0.f};
    #pragma unroll
    for (int k=0;k<4;k++){
      short8 hf[4];
      #pragma unroll
      for (int s=0;s<4;s++) hf[s] = ldf(hbuf + (s*16+l15)*ASTR + k*32 + q*8);
      #pragma unroll
      for (int tt=0;tt<2;tt++){
        int ec = w*32 + tt*16 + l15;
        short8 bf = ldf(We2T + (size_t)ec*128 + k*32 + q*8);
        #pragma unroll
        for (int s=0;s<4;s++)
          acc[tt][s] = __builtin_amdgcn_mfma_f32_16x16x32_bf16(hf[s], bf, acc[tt][s],0,0,0);
      }
    }
    #pragma unroll
    for (int tt=0;tt<2;tt++){
      int ec = w*32 + tt*16 + l15;
      float bb = be2[ec];
      #pragma unroll
      for (int s=0;s<4;s++)
        #pragma unroll
        for (int r=0;r<4;r++){
          int row = s*16 + q*4 + r;
          out_edges[(size_t)(p0+row)*128 + ec] = res[tt][s][r] + acc[tt][s][r] + bb;
        }
    }
  }
}

// ---- softmax stats over q axis: per (b,h,ki) max + 1/sum ----
__global__ __launch_bounds__(128) void k_stats(const float* __restrict__ logits,
                                               float* __restrict__ mstat,
                                               float* __restrict__ sstat){
  int bh = blockIdx.x, ki = threadIdx.x;
  const float* base = logits + (size_t)bh*16384 + ki;
  float mx = -3.4e38f;
  #pragma unroll 8
  for (int qi = 0; qi < 128; qi++) mx = fmaxf(mx, base[(size_t)qi*128]);
  float s = 0.f;
  #pragma unroll 8
  for (int qi = 0; qi < 128; qi++) s += __expf(base[(size_t)qi*128] - mx);
  mstat[bh*128 + ki] = mx;
  sstat[bh*128 + ki] = 1.f/s;
}

// ---- nodeB (grid 128 = 32 rowgroups x 4 slices): wv(on-the-fly softmax)->Wno+res->film2->mlp1 ----
#define AB 272
__global__ __launch_bounds__(256) void k_nodeB(
    const float* __restrict__ logits, const float* __restrict__ mstat, const float* __restrict__ sstat,
    const unsigned short* __restrict__ vT,
    const float* __restrict__ nodes, const float* __restrict__ cond,
    const unsigned short* __restrict__ WnoT, const float* __restrict__ bno,
    const unsigned short* __restrict__ Wn1T, const float* __restrict__ bn1,
    float* __restrict__ nodes1ws, unsigned short* __restrict__ hiddenB){
  __shared__ __align__(16) unsigned short abuf[16*AB];
  __shared__ float redS[16][4], redQ[16][4], mrow[16], irow[16];
  int t = threadIdx.x;
  int rg = blockIdx.x >> 2, slice = blockIdx.x & 3;
  int b = rg >> 3, n0 = (rg & 7)*16;
  int w = t >> 6, l15 = t & 15, q = (t & 63) >> 4;

  // P0: wv (K=128), attn computed on the fly from logits + stats
  #pragma unroll
  for (int h2=0; h2<2; h2++){
    int h = w*2 + h2;
    const float* lp = logits + ((size_t)(b*8+h)*128 + n0 + l15)*128;
    const float* mp = mstat + (size_t)(b*8+h)*128;
    const float* sp = sstat + (size_t)(b*8+h)*128;
    short8 af[4];
    #pragma unroll
    for (int k=0;k<4;k++){
      int kb = q*8 + k*32;
      float4 x0 = *(const float4*)(lp + kb);
      float4 x1 = *(const float4*)(lp + kb + 4);
      float4 m0 = *(const float4*)(mp + kb);
      float4 m1 = *(const float4*)(mp + kb + 4);
      float4 s0 = *(const float4*)(sp + kb);
      float4 s1 = *(const float4*)(sp + kb + 4);
      short8 v;
      v[0] = (short)f2b(__expf(x0.x - m0.x)*s0.x);
      v[1] = (short)f2b(__expf(x0.y - m0.y)*s0.y);
      v[2] = (short)f2b(__expf(x0.z - m0.z)*s0.z);
      v[3] = (short)f2b(__expf(x0.w - m0.w)*s0.w);
      v[4] = (short)f2b(__expf(x1.x - m1.x)*s1.x);
      v[5] = (short)f2b(__expf(x1.y - m1.y)*s1.y);
      v[6] = (short)f2b(__expf(x1.z - m1.z)*s1.z);
      v[7] = (short)f2b(__expf(x1.w - m1.w)*s1.w);
      af[k] = v;
    }
    #pragma unroll
    for (int tt=0;tt<2;tt++){
      int cc = h*32 + tt*16 + l15;
      const unsigned short* bp = vT + (size_t)(b*256+cc)*128 + q*8;
      f32x4 acc = {0.f,0.f,0.f,0.f};
      #pragma unroll
      for (int k=0;k<4;k++) acc = __builtin_amdgcn_mfma_f32_16x16x32_bf16(af[k], ldf(bp + k*32), acc,0,0,0);
      #pragma unroll
      for (int r=0;r<4;r++) abuf[(q*4+r)*AB + cc] = f2b(acc[r]);
    }
  }
  __syncthreads();

  float res[4][4];
  {
    short8 aw[8];
    #pragma unroll
    for (int k=0;k<8;k++) aw[k] = ldf(abuf + l15*AB + k*32 + q*8);
    #pragma unroll
    for (int tt=0;tt<4;tt++){
      int cc = w*64 + tt*16 + l15;
      const unsigned short* bp = WnoT + (size_t)cc*256 + q*8;
      f32x4 acc = {0.f,0.f,0.f,0.f};
      #pragma unroll
      for (int k=0;k<8;k++) acc = __builtin_amdgcn_mfma_f32_16x16x32_bf16(aw[k], ldf(bp + k*32), acc,0,0,0);
      float bb = bno[cc];
      #pragma unroll
      for (int r=0;r<4;r++)
        res[tt][r] = nodes[(size_t)(b*128+n0+q*4+r)*256 + cc] + acc[r] + bb;
    }
  }
  #pragma unroll
  for (int r=0;r<4;r++){
    float ps = res[0][r]+res[1][r]+res[2][r]+res[3][r];
    float p2 = res[0][r]*res[0][r]+res[1][r]*res[1][r]+res[2][r]*res[2][r]+res[3][r]*res[3][r];
    ps += __shfl_xor(ps,1); ps += __shfl_xor(ps,2); ps += __shfl_xor(ps,4); ps += __shfl_xor(ps,8);
    p2 += __shfl_xor(p2,1); p2 += __shfl_xor(p2,2); p2 += __shfl_xor(p2,4); p2 += __shfl_xor(p2,8);
    if (l15 == 0){ redS[q*4+r][w] = ps; redQ[q*4+r][w] = p2; }
  }
  __syncthreads();
  if (t < 16){
    float s = redS[t][0]+redS[t][1]+redS[t][2]+redS[t][3];
    float s2 = redQ[t][0]+redQ[t][1]+redQ[t][2]+redQ[t][3];
    float m = s*(1.f/256);
    mrow[t] = m; irow[t] = rsqrtf(s2*(1.f/256) - m*m + 1e-5f);
  }
  __syncthreads();
  #pragma unroll
  for (int tt=0;tt<4;tt++){
    int cc = w*64 + tt*16 + l15;
    float mul = 1.f + cond[b*1024 + 512 + cc];
    float add = cond[b*1024 + 768 + cc];
    #pragma unroll
    for (int r=0;r<4;r++){
      int row = q*4+r;
      abuf[row*AB + cc] = f2b(lrelu((res[tt][r] - mrow[row])*irow[row]*mul + add));
    }
  }
  if (slice == 0){
    #pragma unroll
    for (int tt=0;tt<4;tt++){
      int cc = w*64 + tt*16 + l15;
      #pragma unroll
      for (int r=0;r<4;r++)
        nodes1ws[(size_t)(rg*16 + q*4+r)*256 + cc] = res[tt][r];
    }
  }
  __syncthreads();
  {
    short8 a2[8];
    #pragma unroll
    for (int k=0;k<8;k++) a2[k] = ldf(abuf + l15*AB + k*32 + q*8);
    #pragma unroll
    for (int tt=0;tt<4;tt++){
      int cc = slice*256 + w*64 + tt*16 + l15;
      const unsigned short* bp = Wn1T + (size_t)cc*256 + q*8;
      f32x4 acc = {0.f,0.f,0.f,0.f};
      #pragma unroll
      for (int k=0;k<8;k++) acc = __builtin_amdgcn_mfma_f32_16x16x32_bf16(a2[k], ldf(bp + k*32), acc,0,0,0);
      float bb = bn1[cc];
      #pragma unroll
      for (int r=0;r<4;r++)
        hiddenB[((size_t)rg*16 + q*4+r)*1024 + cc] = f2b(lrelu(acc[r] + bb));
    }
  }
}

// ---- nodeC (grid 128 = 32 rowgroups x 4 col-slices): mlp2 (K=1024, dual-chain) + residual ----
__global__ __launch_bounds__(256) void k_nodeC(
    const unsigned short* __restrict__ hiddenB, const float* __restrict__ nodes1ws,
    const unsigned short* __restrict__ Wn2T, const float* __restrict__ bn2,
    float* __restrict__ out_nodes){
  int t = threadIdx.x;
  int rg = blockIdx.x >> 2, cs = blockIdx.x & 3;
  int w = t >> 6, l15 = t & 15, q = (t & 63) >> 4;
  int cc = cs*64 + w*16 + l15;
  const unsigned short* ap = hiddenB + ((size_t)rg*16 + l15)*1024 + q*8;
  const unsigned short* bp = Wn2T + (size_t)cc*1024 + q*8;
  f32x4 acc0 = {0.f,0.f,0.f,0.f}, acc1 = acc0;
  #pragma unroll
  for (int k=0;k<16;k++){
    acc0 = __builtin_amdgcn_mfma_f32_16x16x32_bf16(ldf(ap + k*32), ldf(bp + k*32), acc0,0,0,0);
    acc1 = __builtin_amdgcn_mfma_f32_16x16x32_bf16(ldf(ap + (k+16)*32), ldf(bp + (k+16)*32), acc1,0,0,0);
  }
  f32x4 acc = acc0 + acc1;
  float bb = bn2[cc];
  #pragma unroll
  for (int r=0;r<4;r++){
    size_t row = (size_t)rg*16 + q*4 + r;
    out_nodes[row*256 + cc] = nodes1ws[row*256 + cc] + acc[r] + bb;
  }
}

extern "C" void kernel_launch(void* const* d_in, const int* in_sizes, int n_inp,
                              void* d_out, int out_size, void* d_ws, size_t ws_size,
                              hipStream_t stream){
  const float* nodes = (const float*)d_in[0];
  const float* edges = (const float*)d_in[1];
  const float* conds = (const float*)d_in[2];
  const float* Wc   = (const float*)d_in[3];
  const float* bc   = (const float*)d_in[4];
  const float* Wqkv = (const float*)d_in[5];
  const float* bqkv = (const float*)d_in[6];
  const float* Wss  = (const float*)d_in[7];
  const float* bss  = (const float*)d_in[8];
  const float* Wno  = (const float*)d_in[9];
  const float* bno  = (const float*)d_in[10];
  const float* Weo  = (const float*)d_in[11];
  const float* beo  = (const float*)d_in[12];
  const float* Wn1  = (const float*)d_in[13];
  const float* bn1  = (const float*)d_in[14];
  const float* Wn2  = (const float*)d_in[15];
  const float* bn2  = (const float*)d_in[16];
  const float* We1  = (const float*)d_in[17];
  const float* be1  = (const float*)d_in[18];
  const float* We2  = (const float*)d_in[19];
  const float* be2  = (const float*)d_in[20];

  float* ws       = (float*)d_ws;
  float* cond     = ws;                       // 4096
  float* qbuf     = cond + 4096;              // 131072
  float* kT       = qbuf + 131072;            // 131072
  float* logits   = kT + 131072;              // 524288  [b,h,qi,ki]
  float* nodes1ws = logits + 524288;          // 131072
  float* mstat    = nodes1ws + 131072;        // 4096
  float* sstat    = mstat + 4096;             // 4096
  unsigned short* vT      = (unsigned short*)(sstat + 4096);  // 131072 us
  unsigned short* hiddenB = vT + 131072;                      // 524288 us
  unsigned short* wbf     = hiddenB + 524288;                 // 917504 us

  unsigned short* WssT  = wbf;
  unsigned short* WeoT  = wbf + 65536;
  unsigned short* We1T  = wbf + 98304;
  unsigned short* We2T  = wbf + 114688;
  unsigned short* WqkvT = wbf + 131072;
  unsigned short* WnoT  = wbf + 327680;
  unsigned short* Wn1T  = wbf + 393216;
  unsigned short* Wn2T  = wbf + 655360;

  float* out_nodes = (float*)d_out;
  float* out_edges = out_nodes + 131072;

  k_setup<<<912, 256, 0, stream>>>(Wss, Weo, We1, We2, Wqkv, Wno, Wn1, Wn2,
                                   conds, Wc, bc, wbf, cond);
  k_nodeA<<<128, 256, 0, stream>>>(nodes, cond, WqkvT, bqkv, qbuf, kT, vT);
  k_edge<<<BB*NN*NN/64, 256, 0, stream>>>(edges, qbuf, kT, WssT, bss, WeoT, beo,
                                          We1T, be1, We2T, be2, logits, out_edges);
  k_stats<<<BB*NH, 128, 0, stream>>>(logits, mstat, sstat);
  k_nodeB<<<128, 256, 0, stream>>>(logits, mstat, sstat, vT, nodes, cond,
                                   WnoT, bno, Wn1T, bn1, nodes1ws, hiddenB);
  k_nodeC<<<128, 256, 0, stream>>>(hiddenB, nodes1ws, Wn2T, bn2, out_nodes);
}

// Round 11
// 214.812 us; speedup vs baseline: 1.1151x; 1.1151x over previous
//
#include <hip/hip_runtime.h>
#include <hip/hip_bf16.h>

#define BB 4
#define NN 128
#define NH 8

typedef __attribute__((ext_vector_type(8))) short short8;
typedef __attribute__((ext_vector_type(4))) float f32x4;

__device__ __forceinline__ float lrelu(float x){ return fmaxf(x, 0.1f*x); }
__device__ __forceinline__ unsigned short f2b(float x){
  __hip_bfloat16 h = __float2bfloat16(x);
  return *reinterpret_cast<unsigned short*>(&h);
}
__device__ __forceinline__ short8 ldf(const unsigned short* p){ return *(const short8*)p; }

// wbf ushort offsets: WssT 0 [512x128] | WeoT 65536 [128x256] | We1T 98304 [128x128]
// We2T 114688 [128x128] | WqkvT 131072 [768x256] | WnoT 327680 [256x256]
// Wn1T 393216 [1024x256] | Wn2T 655360 [256x1024]

// ---- setup: LDS-tiled bf16 transposes (tiles 0..895) + cond GEMM (896..911) ----
__global__ __launch_bounds__(256) void k_setup(
    const float* Wss, const float* Weo, const float* We1, const float* We2,
    const float* Wqkv, const float* Wno, const float* Wn1, const float* Wn2,
    const float* conds, const float* Wc, const float* bc,
    unsigned short* wbf, float* cond){
  __shared__ float tile[32][33];
  __shared__ float c[256];
  int bid = blockIdx.x, t = threadIdx.x;
  if (bid < 896){
    const float* src; int K, N; size_t doff; int tid;
    if      (bid < 64)  { src=Wss;  K=128;  N=512;  doff=0;      tid=bid; }
    else if (bid < 96)  { src=Weo;  K=256;  N=128;  doff=65536;  tid=bid-64; }
    else if (bid < 112) { src=We1;  K=128;  N=128;  doff=98304;  tid=bid-96; }
    else if (bid < 128) { src=We2;  K=128;  N=128;  doff=114688; tid=bid-112; }
    else if (bid < 320) { src=Wqkv; K=256;  N=768;  doff=131072; tid=bid-128; }
    else if (bid < 384) { src=Wno;  K=256;  N=256;  doff=327680; tid=bid-320; }
    else if (bid < 640) { src=Wn1;  K=256;  N=1024; doff=393216; tid=bid-384; }
    else                { src=Wn2;  K=1024; N=256;  doff=655360; tid=bid-640; }
    int ntk = K >> 5;
    int k0 = (tid % ntk) * 32, n0 = (tid / ntk) * 32;
    int r = t >> 3, c4 = (t & 7) * 4;
    float4 v = *(const float4*)(src + (size_t)(k0+r)*N + n0 + c4);
    tile[r][c4+0]=v.x; tile[r][c4+1]=v.y; tile[r][c4+2]=v.z; tile[r][c4+3]=v.w;
    __syncthreads();
    ushort4 o;
    o.x = f2b(tile[c4+0][r]); o.y = f2b(tile[c4+1][r]);
    o.z = f2b(tile[c4+2][r]); o.w = f2b(tile[c4+3][r]);
    *(ushort4*)(wbf + doff + (size_t)(n0+r)*K + k0 + c4) = o;
  } else {
    int i = bid - 896;
    int b = i >> 2, j = (i&3)*256 + t;
    c[t] = conds[(size_t)b*256 + t];
    __syncthreads();
    float acc = bc[j];
    for (int kk = 0; kk < 256; kk++) acc += c[kk]*Wc[(size_t)kk*1024 + j];
    cond[b*1024 + j] = acc;
  }
}

// ---- film1 + qkv (MFMA). 16 rows x 128-col slice per block, grid 192 ----
#define NSTR 260
__global__ __launch_bounds__(256) void k_nodeA(const float* __restrict__ nodes,
    const float* __restrict__ cond, const unsigned short* __restrict__ WqkvT,
    const float* __restrict__ bqkv, float* __restrict__ qbuf,
    float* __restrict__ kT, unsigned short* __restrict__ vT){
  __shared__ float nbuf[16*NSTR];
  __shared__ __align__(16) unsigned short abuf[16*272];
  __shared__ float psum[256], psq[256], mrow[16], irow[16];
  int t = threadIdx.x;
  int rg = blockIdx.x / 6, slice = blockIdx.x % 6;
  int b = rg >> 3, n0 = (rg & 7)*16;
  int l = t & 63, w = t >> 6, l15 = l & 15, q = l >> 4;

  const float4* src = (const float4*)(nodes + ((size_t)(b*128+n0))*256);
  #pragma unroll
  for (int i = 0; i < 4; i++){
    int f = t + i*256; int r = f >> 6, c4 = f & 63;
    *(float4*)(nbuf + r*NSTR + c4*4) = src[f];
  }
  __syncthreads();
  {
    int r = t >> 4, p = t & 15;
    float s = 0.f, s2 = 0.f;
    #pragma unroll
    for (int i = 0; i < 16; i++){ float v = nbuf[r*NSTR + p + 16*i]; s += v; s2 += v*v; }
    psum[t] = s; psq[t] = s2;
  }
  __syncthreads();
  if (t < 16){
    float s = 0.f, s2 = 0.f;
    #pragma unroll
    for (int i = 0; i < 16; i++){ s += psum[t*16+i]; s2 += psq[t*16+i]; }
    float m = s*(1.f/256);
    mrow[t] = m; irow[t] = rsqrtf(s2*(1.f/256) - m*m + 1e-5f);
  }
  __syncthreads();
  #pragma unroll
  for (int i = 0; i < 16; i++){
    int f = t + i*256; int r = f >> 8, cc = f & 255;
    float x = (nbuf[r*NSTR+cc]-mrow[r])*irow[r]*(1.f+cond[b*1024+cc]) + cond[b*1024+256+cc];
    abuf[r*272+cc] = f2b(lrelu(x));
  }
  __syncthreads();
  short8 af[8];
  #pragma unroll
  for (int k = 0; k < 8; k++) af[k] = ldf(abuf + l15*272 + k*32 + q*8);
  #pragma unroll
  for (int tt = 0; tt < 2; tt++){
    int cc = slice*128 + w*32 + tt*16 + l15;
    const unsigned short* bp = WqkvT + (size_t)cc*256 + q*8;
    f32x4 acc = {0.f,0.f,0.f,0.f};
    #pragma unroll
    for (int k = 0; k < 8; k++) acc = __builtin_amdgcn_mfma_f32_16x16x32_bf16(af[k], ldf(bp + k*32), acc,0,0,0);
    float bb = bqkv[cc];
    if (cc < 256){
      #pragma unroll
      for (int r = 0; r < 4; r++) qbuf[(size_t)(b*128+n0+q*4+r)*256 + cc] = acc[r] + bb;
    } else if (cc < 512){
      float4 kv; kv.x = acc[0]+bb; kv.y = acc[1]+bb; kv.z = acc[2]+bb; kv.w = acc[3]+bb;
      *(float4*)(kT + ((size_t)(b*256 + cc-256))*128 + n0 + q*4) = kv;
    } else {
      ushort4 vv; vv.x = f2b(acc[0]+bb); vv.y = f2b(acc[1]+bb); vv.z = f2b(acc[2]+bb); vv.w = f2b(acc[3]+bb);
      *(ushort4*)(vT + ((size_t)(b*256 + cc-512))*128 + n0 + q*4) = vv;
    }
  }
}

// ---- fused edge path, 256 threads, 64 rows/block, grid 1024 (r8, frozen) ----
#define ASTR 144
#define LSTR 264
__global__ __launch_bounds__(256) void k_edge(
    const float* __restrict__ edges, const float* __restrict__ qbuf, const float* __restrict__ kT,
    const unsigned short* __restrict__ WssT, const float* __restrict__ bss,
    const unsigned short* __restrict__ WeoT, const float* __restrict__ beo,
    const unsigned short* __restrict__ We1T, const float* __restrict__ be1,
    const unsigned short* __restrict__ We2T, const float* __restrict__ be2,
    float* __restrict__ logitsT, float* __restrict__ out_edges){
  __shared__ __align__(16) unsigned short abuf[64*ASTR];
  __shared__ __align__(16) unsigned short lbuf[64*LSTR];
  __shared__ float qvs[256];
  __shared__ float redS[64][4], redQ[64][4], mrow[64], irow[64];

  int t = threadIdx.x;
  int p0 = blockIdx.x * 64;
  int b  = p0 >> 14, qi = (p0 >> 7) & 127, ki0 = p0 & 127;
  int w = t >> 6, l15 = t & 15, q = (t & 63) >> 4;

  {
    qvs[t] = qbuf[(size_t)(b*128 + qi)*256 + t];
    const float4* src = (const float4*)(edges + (size_t)p0*128);
    #pragma unroll
    for (int i=0;i<8;i++){
      int idx = t + i*256;
      float4 ev = src[idx];
      int r = idx >> 5, c4 = idx & 31;
      float s  = ev.x + ev.y + ev.z + ev.w;
      float s2 = ev.x*ev.x + ev.y*ev.y + ev.z*ev.z + ev.w*ev.w;
      #pragma unroll
      for (int mm=1; mm<32; mm<<=1){ s += __shfl_xor(s,mm); s2 += __shfl_xor(s2,mm); }
      float m = s*(1.f/128);
      float inv = rsqrtf(s2*(1.f/128) - m*m + 1e-5f);
      ushort4 pk;
      pk.x = f2b(lrelu((ev.x - m)*inv)); pk.y = f2b(lrelu((ev.y - m)*inv));
      pk.z = f2b(lrelu((ev.z - m)*inv)); pk.w = f2b(lrelu((ev.w - m)*inv));
      *(ushort4*)(abuf + r*ASTR + c4*4) = pk;
    }
  }
  __syncthreads();

  const float isd = 0.17677669529663687f;
  {
    short8 af[4][4];
    #pragma unroll
    for (int s=0;s<4;s++)
      #pragma unroll
      for (int k=0;k<4;k++) af[s][k] = ldf(abuf + (s*16+l15)*ASTR + k*32 + q*8);
    #pragma unroll
    for (int h2=0; h2<2; h2++){
      int h = w*2 + h2;
      float ps[4][4] = {{0,0,0,0},{0,0,0,0},{0,0,0,0},{0,0,0,0}};
      #pragma unroll
      for (int tt=0; tt<2; tt++){
        int cc = h*32 + tt*16 + l15;
        const unsigned short* bsp = WssT + (size_t)cc*128 + q*8;
        const unsigned short* bcp = WssT + (size_t)(cc+256)*128 + q*8;
        f32x4 aS[4], aC[4];
        #pragma unroll
        for (int s=0;s<4;s++){ aS[s]={0.f,0.f,0.f,0.f}; aC[s]={0.f,0.f,0.f,0.f}; }
        #pragma unroll
        for (int k=0;k<4;k++){
          short8 b0 = ldf(bsp + k*32);
          short8 b1 = ldf(bcp + k*32);
          #pragma unroll
          for (int s=0;s<4;s++){
            aS[s] = __builtin_amdgcn_mfma_f32_16x16x32_bf16(af[s][k], b0, aS[s],0,0,0);
            aC[s] = __builtin_amdgcn_mfma_f32_16x16x32_bf16(af[s][k], b1, aC[s],0,0,0);
          }
        }
        float bS = bss[cc], bC = bss[256+cc], qv = qvs[cc];
        #pragma unroll
        for (int s=0;s<4;s++){
          float4 kv4 = *(const float4*)(kT + ((size_t)(b*256+cc))*128 + ki0 + s*16 + q*4);
          float kvv[4] = {kv4.x, kv4.y, kv4.z, kv4.w};
          #pragma unroll
          for (int r=0;r<4;r++){
            int row = s*16 + q*4 + r;
            float ne = qv*kvv[r]*(1.f + aC[s][r] + bC) + aS[s][r] + bS;
            lbuf[row*LSTR + cc] = f2b(lrelu(ne));
            ps[s][r] += ne;
          }
        }
      }
      #pragma unroll
      for (int s=0;s<4;s++)
        #pragma unroll
        for (int r=0;r<4;r++){
          float v = ps[s][r];
          v += __shfl_xor(v,1); v += __shfl_xor(v,2);
          v += __shfl_xor(v,4); v += __shfl_xor(v,8);
          if (l15 == 0){
            int ki = ki0 + s*16 + q*4 + r;
            logitsT[((size_t)(b*8+h)*128 + ki)*128 + qi] = v * isd;
          }
        }
    }
  }
  __syncthreads();

  float res[2][4][4];
  {
    f32x4 acc[2][4];
    #pragma unroll
    for (int tt=0;tt<2;tt++)
      #pragma unroll
      for (int s=0;s<4;s++) acc[tt][s] = {0.f,0.f,0.f,0.f};
    #pragma unroll
    for (int k=0;k<8;k++){
      short8 lf[4];
      #pragma unroll
      for (int s=0;s<4;s++) lf[s] = ldf(lbuf + (s*16+l15)*LSTR + k*32 + q*8);
      #pragma unroll
      for (int tt=0;tt<2;tt++){
        int ec = w*32 + tt*16 + l15;
        short8 bf = ldf(WeoT + (size_t)ec*256 + k*32 + q*8);
        #pragma unroll
        for (int s=0;s<4;s++)
          acc[tt][s] = __builtin_amdgcn_mfma_f32_16x16x32_bf16(lf[s], bf, acc[tt][s],0,0,0);
      }
    }
    #pragma unroll
    for (int tt=0;tt<2;tt++){
      int ec = w*32 + tt*16 + l15;
      float bb = beo[ec];
      #pragma unroll
      for (int s=0;s<4;s++)
        #pragma unroll
        for (int r=0;r<4;r++){
          int row = s*16 + q*4 + r;
          res[tt][s][r] = edges[(size_t)(p0+row)*128 + ec] + acc[tt][s][r] + bb;
        }
    }
  }
  #pragma unroll
  for (int s=0;s<4;s++)
    #pragma unroll
    for (int r=0;r<4;r++){
      float ps = res[0][s][r] + res[1][s][r];
      float p2 = res[0][s][r]*res[0][s][r] + res[1][s][r]*res[1][s][r];
      ps += __shfl_xor(ps,1); ps += __shfl_xor(ps,2); ps += __shfl_xor(ps,4); ps += __shfl_xor(ps,8);
      p2 += __shfl_xor(p2,1); p2 += __shfl_xor(p2,2); p2 += __shfl_xor(p2,4); p2 += __shfl_xor(p2,8);
      if (l15 == 0){ redS[s*16+q*4+r][w] = ps; redQ[s*16+q*4+r][w] = p2; }
    }
  __syncthreads();
  if (t < 64){
    float s = redS[t][0]+redS[t][1]+redS[t][2]+redS[t][3];
    float s2 = redQ[t][0]+redQ[t][1]+redQ[t][2]+redQ[t][3];
    float m = s*(1.f/128);
    mrow[t] = m; irow[t] = rsqrtf(s2*(1.f/128) - m*m + 1e-5f);
  }
  __syncthreads();
  #pragma unroll
  for (int tt=0;tt<2;tt++){
    int ec = w*32 + tt*16 + l15;
    #pragma unroll
    for (int s=0;s<4;s++)
      #pragma unroll
      for (int r=0;r<4;r++){
        int row = s*16 + q*4 + r;
        abuf[row*ASTR + ec] = f2b(lrelu((res[tt][s][r] - mrow[row])*irow[row]));
      }
  }
  __syncthreads();

  unsigned short* hbuf = lbuf;
  {
    f32x4 acc[2][4];
    #pragma unroll
    for (int tt=0;tt<2;tt++)
      #pragma unroll
      for (int s=0;s<4;s++) acc[tt][s] = {0.f,0.f,0.f,0.f};
    #pragma unroll
    for (int k=0;k<4;k++){
      short8 af2[4];
      #pragma unroll
      for (int s=0;s<4;s++) af2[s] = ldf(abuf + (s*16+l15)*ASTR + k*32 + q*8);
      #pragma unroll
      for (int tt=0;tt<2;tt++){
        int ec = w*32 + tt*16 + l15;
        short8 bf = ldf(We1T + (size_t)ec*128 + k*32 + q*8);
        #pragma unroll
        for (int s=0;s<4;s++)
          acc[tt][s] = __builtin_amdgcn_mfma_f32_16x16x32_bf16(af2[s], bf, acc[tt][s],0,0,0);
      }
    }
    #pragma unroll
    for (int tt=0;tt<2;tt++){
      int ec = w*32 + tt*16 + l15;
      float bb = be1[ec];
      #pragma unroll
      for (int s=0;s<4;s++)
        #pragma unroll
        for (int r=0;r<4;r++)
          hbuf[(s*16+q*4+r)*ASTR + ec] = f2b(lrelu(acc[tt][s][r] + bb));
    }
  }
  __syncthreads();
  {
    f32x4 acc[2][4];
    #pragma unroll
    for (int tt=0;tt<2;tt++)
      #pragma unroll
      for (int s=0;s<4;s++) acc[tt][s] = {0.f,0.f,0.f,0.f};
    #pragma unroll
    for (int k=0;k<4;k++){
      short8 hf[4];
      #pragma unroll
      for (int s=0;s<4;s++) hf[s] = ldf(hbuf + (s*16+l15)*ASTR + k*32 + q*8);
      #pragma unroll
      for (int tt=0;tt<2;tt++){
        int ec = w*32 + tt*16 + l15;
        short8 bf = ldf(We2T + (size_t)ec*128 + k*32 + q*8);
        #pragma unroll
        for (int s=0;s<4;s++)
          acc[tt][s] = __builtin_amdgcn_mfma_f32_16x16x32_bf16(hf[s], bf, acc[tt][s],0,0,0);
      }
    }
    #pragma unroll
    for (int tt=0;tt<2;tt++){
      int ec = w*32 + tt*16 + l15;
      float bb = be2[ec];
      #pragma unroll
      for (int s=0;s<4;s++)
        #pragma unroll
        for (int r=0;r<4;r++){
          int row = s*16 + q*4 + r;
          out_edges[(size_t)(p0+row)*128 + ec] = res[tt][s][r] + acc[tt][s][r] + bb;
        }
    }
  }
}

// ---- softmax over q axis; grid 256 = (b,h) x 8 ki-slices (r8, frozen) ----
__global__ __launch_bounds__(256) void k_attn(const float* __restrict__ logitsT,
                                              unsigned short* __restrict__ attnB){
  __shared__ float tile[16][132];
  __shared__ float mS[16], sS[16];
  int bh = blockIdx.x >> 3, slice = blockIdx.x & 7;
  int t = threadIdx.x, w = t >> 6, l = t & 63;
  const float* base = logitsT + (size_t)bh*16384 + slice*16*128;
  #pragma unroll
  for (int i = 0; i < 8; i++){
    int idx = t + i*256; int ki = idx >> 7, qq = idx & 127;
    tile[ki][qq] = base[ki*128 + qq];
  }
  __syncthreads();
  #pragma unroll
  for (int i = 0; i < 4; i++){
    int ki = w*4 + i;
    float x0 = tile[ki][l], x1 = tile[ki][l+64];
    float mx = fmaxf(x0, x1);
    #pragma unroll
    for (int m=1;m<64;m<<=1) mx = fmaxf(mx, __shfl_xor(mx,m));
    float s = __expf(x0-mx) + __expf(x1-mx);
    #pragma unroll
    for (int m=1;m<64;m<<=1) s += __shfl_xor(s,m);
    if (l == 0){ mS[ki] = mx; sS[ki] = 1.f/s; }
  }
  __syncthreads();
  unsigned short* obase = attnB + (size_t)bh*16384 + slice*16;
  #pragma unroll
  for (int i = 0; i < 8; i++){
    int idx = t + i*256; int qq = idx >> 4, kk = idx & 15;
    obase[qq*128 + kk] = f2b(__expf(tile[kk][qq] - mS[kk]) * sS[kk]);
  }
}

// ---- nodeB (grid 256 = 32 rowgroups x 8 slices): wv->Wno+res->film2->mlp1 slice ----
// slice 0 also writes out_nodes = nodes1 + bn2 (base for nodeC's atomic partials)
#define AB 272
__global__ __launch_bounds__(256) void k_nodeB(
    const unsigned short* __restrict__ attnB, const unsigned short* __restrict__ vT,
    const float* __restrict__ nodes, const float* __restrict__ cond,
    const unsigned short* __restrict__ WnoT, const float* __restrict__ bno,
    const unsigned short* __restrict__ Wn1T, const float* __restrict__ bn1,
    const float* __restrict__ bn2,
    float* __restrict__ out_nodes, unsigned short* __restrict__ hiddenB){
  __shared__ __align__(16) unsigned short abuf[16*AB];
  __shared__ float redS[16][4], redQ[16][4], mrow[16], irow[16];
  int t = threadIdx.x;
  int rg = blockIdx.x >> 3, slice = blockIdx.x & 7;
  int b = rg >> 3, n0 = (rg & 7)*16;
  int w = t >> 6, l15 = t & 15, q = (t & 63) >> 4;

  #pragma unroll
  for (int h2=0; h2<2; h2++){
    int h = w*2 + h2;
    const unsigned short* ap = attnB + ((size_t)(b*8+h)*128 + n0 + l15)*128 + q*8;
    short8 af[4];
    #pragma unroll
    for (int k=0;k<4;k++) af[k] = ldf(ap + k*32);
    #pragma unroll
    for (int tt=0;tt<2;tt++){
      int cc = h*32 + tt*16 + l15;
      const unsigned short* bp = vT + (size_t)(b*256+cc)*128 + q*8;
      f32x4 acc = {0.f,0.f,0.f,0.f};
      #pragma unroll
      for (int k=0;k<4;k++) acc = __builtin_amdgcn_mfma_f32_16x16x32_bf16(af[k], ldf(bp + k*32), acc,0,0,0);
      #pragma unroll
      for (int r=0;r<4;r++) abuf[(q*4+r)*AB + cc] = f2b(acc[r]);
    }
  }
  __syncthreads();

  float res[4][4];
  {
    short8 aw[8];
    #pragma unroll
    for (int k=0;k<8;k++) aw[k] = ldf(abuf + l15*AB + k*32 + q*8);
    #pragma unroll
    for (int tt=0;tt<4;tt++){
      int cc = w*64 + tt*16 + l15;
      const unsigned short* bp = WnoT + (size_t)cc*256 + q*8;
      f32x4 acc = {0.f,0.f,0.f,0.f};
      #pragma unroll
      for (int k=0;k<8;k++) acc = __builtin_amdgcn_mfma_f32_16x16x32_bf16(aw[k], ldf(bp + k*32), acc,0,0,0);
      float bb = bno[cc];
      #pragma unroll
      for (int r=0;r<4;r++)
        res[tt][r] = nodes[(size_t)(b*128+n0+q*4+r)*256 + cc] + acc[r] + bb;
    }
  }
  #pragma unroll
  for (int r=0;r<4;r++){
    float ps = res[0][r]+res[1][r]+res[2][r]+res[3][r];
    float p2 = res[0][r]*res[0][r]+res[1][r]*res[1][r]+res[2][r]*res[2][r]+res[3][r]*res[3][r];
    ps += __shfl_xor(ps,1); ps += __shfl_xor(ps,2); ps += __shfl_xor(ps,4); ps += __shfl_xor(ps,8);
    p2 += __shfl_xor(p2,1); p2 += __shfl_xor(p2,2); p2 += __shfl_xor(p2,4); p2 += __shfl_xor(p2,8);
    if (l15 == 0){ redS[q*4+r][w] = ps; redQ[q*4+r][w] = p2; }
  }
  __syncthreads();
  if (t < 16){
    float s = redS[t][0]+redS[t][1]+redS[t][2]+redS[t][3];
    float s2 = redQ[t][0]+redQ[t][1]+redQ[t][2]+redQ[t][3];
    float m = s*(1.f/256);
    mrow[t] = m; irow[t] = rsqrtf(s2*(1.f/256) - m*m + 1e-5f);
  }
  __syncthreads();
  #pragma unroll
  for (int tt=0;tt<4;tt++){
    int cc = w*64 + tt*16 + l15;
    float mul = 1.f + cond[b*1024 + 512 + cc];
    float add = cond[b*1024 + 768 + cc];
    #pragma unroll
    for (int r=0;r<4;r++){
      int row = q*4+r;
      abuf[row*AB + cc] = f2b(lrelu((res[tt][r] - mrow[row])*irow[row]*mul + add));
    }
  }
  if (slice == 0){
    #pragma unroll
    for (int tt=0;tt<4;tt++){
      int cc = w*64 + tt*16 + l15;
      float bb = bn2[cc];
      #pragma unroll
      for (int r=0;r<4;r++)
        out_nodes[(size_t)(rg*16 + q*4+r)*256 + cc] = res[tt][r] + bb;
    }
  }
  __syncthreads();
  {
    short8 a2[8];
    #pragma unroll
    for (int k=0;k<8;k++) a2[k] = ldf(abuf + l15*AB + k*32 + q*8);
    #pragma unroll
    for (int tt=0;tt<2;tt++){
      int cc = slice*128 + w*32 + tt*16 + l15;
      const unsigned short* bp = Wn1T + (size_t)cc*256 + q*8;
      f32x4 acc = {0.f,0.f,0.f,0.f};
      #pragma unroll
      for (int k=0;k<8;k++) acc = __builtin_amdgcn_mfma_f32_16x16x32_bf16(a2[k], ldf(bp + k*32), acc,0,0,0);
      float bb = bn1[cc];
      #pragma unroll
      for (int r=0;r<4;r++)
        hiddenB[((size_t)rg*16 + q*4+r)*1024 + cc] = f2b(lrelu(acc[r] + bb));
    }
  }
}

// ---- nodeC (grid 512 = 32 rg x 4 col-slices x 4 K-slices): mlp2 partial + atomicAdd ----
__global__ __launch_bounds__(256) void k_nodeC(
    const unsigned short* __restrict__ hiddenB,
    const unsigned short* __restrict__ Wn2T,
    float* __restrict__ out_nodes){
  int t = threadIdx.x;
  int rg = blockIdx.x >> 4;
  int rem = blockIdx.x & 15;
  int cs = rem >> 2, ks = rem & 3;
  int w = t >> 6, l15 = t & 15, q = (t & 63) >> 4;
  int cc = cs*64 + w*16 + l15;
  const unsigned short* ap = hiddenB + ((size_t)rg*16 + l15)*1024 + ks*256 + q*8;
  const unsigned short* bp = Wn2T + (size_t)cc*1024 + ks*256 + q*8;
  f32x4 acc0 = {0.f,0.f,0.f,0.f}, acc1 = acc0;
  #pragma unroll
  for (int k=0;k<4;k++){
    acc0 = __builtin_amdgcn_mfma_f32_16x16x32_bf16(ldf(ap + k*32), ldf(bp + k*32), acc0,0,0,0);
    acc1 = __builtin_amdgcn_mfma_f32_16x16x32_bf16(ldf(ap + (k+4)*32), ldf(bp + (k+4)*32), acc1,0,0,0);
  }
  f32x4 acc = acc0 + acc1;
  #pragma unroll
  for (int r=0;r<4;r++){
    size_t row = (size_t)rg*16 + q*4 + r;
    atomicAdd(&out_nodes[row*256 + cc], acc[r]);
  }
}

extern "C" void kernel_launch(void* const* d_in, const int* in_sizes, int n_inp,
                              void* d_out, int out_size, void* d_ws, size_t ws_size,
                              hipStream_t stream){
  const float* nodes = (const float*)d_in[0];
  const float* edges = (const float*)d_in[1];
  const float* conds = (const float*)d_in[2];
  const float* Wc   = (const float*)d_in[3];
  const float* bc   = (const float*)d_in[4];
  const float* Wqkv = (const float*)d_in[5];
  const float* bqkv = (const float*)d_in[6];
  const float* Wss  = (const float*)d_in[7];
  const float* bss  = (const float*)d_in[8];
  const float* Wno  = (const float*)d_in[9];
  const float* bno  = (const float*)d_in[10];
  const float* Weo  = (const float*)d_in[11];
  const float* beo  = (const float*)d_in[12];
  const float* Wn1  = (const float*)d_in[13];
  const float* bn1  = (const float*)d_in[14];
  const float* Wn2  = (const float*)d_in[15];
  const float* bn2  = (const float*)d_in[16];
  const float* We1  = (const float*)d_in[17];
  const float* be1  = (const float*)d_in[18];
  const float* We2  = (const float*)d_in[19];
  const float* be2  = (const float*)d_in[20];

  float* ws       = (float*)d_ws;
  float* cond     = ws;                       // 4096
  float* qbuf     = cond + 4096;              // 131072
  float* kT       = qbuf + 131072;            // 131072
  float* logitsT  = kT + 131072;              // 524288  [b,h,ki,qi]
  unsigned short* attnB   = (unsigned short*)(logitsT + 524288); // 524288 us
  unsigned short* vT      = attnB + 524288;                      // 131072 us
  unsigned short* hiddenB = vT + 131072;                         // 524288 us
  unsigned short* wbf     = hiddenB + 524288;                    // 917504 us

  unsigned short* WssT  = wbf;
  unsigned short* WeoT  = wbf + 65536;
  unsigned short* We1T  = wbf + 98304;
  unsigned short* We2T  = wbf + 114688;
  unsigned short* WqkvT = wbf + 131072;
  unsigned short* WnoT  = wbf + 327680;
  unsigned short* Wn1T  = wbf + 393216;
  unsigned short* Wn2T  = wbf + 655360;

  float* out_nodes = (float*)d_out;
  float* out_edges = out_nodes + 131072;

  k_setup<<<912, 256, 0, stream>>>(Wss, Weo, We1, We2, Wqkv, Wno, Wn1, Wn2,
                                   conds, Wc, bc, wbf, cond);
  k_nodeA<<<192, 256, 0, stream>>>(nodes, cond, WqkvT, bqkv, qbuf, kT, vT);
  k_edge<<<BB*NN*NN/64, 256, 0, stream>>>(edges, qbuf, kT, WssT, bss, WeoT, beo,
                                          We1T, be1, We2T, be2, logitsT, out_edges);
  k_attn<<<BB*NH*8, 256, 0, stream>>>(logitsT, attnB);
  k_nodeB<<<256, 256, 0, stream>>>(attnB, vT, nodes, cond, WnoT, bno, Wn1T, bn1,
                                   bn2, out_nodes, hiddenB);
  k_nodeC<<<512, 256, 0, stream>>>(hiddenB, Wn2T, out_nodes);
}